// Round 2
// baseline (73349.200 us; speedup 1.0000x reference)
//
#include <hip/hip_runtime.h>

// PQMatcher persistent-kernel version.
// One kernel runs all 256 scan steps; grid = 256 blocks x 256 threads
// (<= 256 CUs -> all co-resident), custom device-scope barrier between
// phases (generation counters, one per sync point, agent-scope atomics).
// v-state lives in LDS for the whole scan (per-bgroup replicated).
// Pre-kernels: k_init (weight folds), k_wuq (hoisted WUq GEMM), k_zero (ctrs).

#define NB 32
#define H 1024
#define H3 3072
#define LQn 256

__device__ __forceinline__ float fsig(float x) { return 1.0f / (1.0f + __expf(-x)); }
__device__ __forceinline__ float ftanh(float x) { return 1.0f - 2.0f / (1.0f + __expf(2.0f * x)); }

// Grid barrier: each id used exactly once per launch (counters pre-zeroed).
__device__ __forceinline__ void gbar(unsigned* __restrict__ ctr, int id) {
  __syncthreads();
  if (threadIdx.x == 0) {
    __threadfence();  // release: make this block's writes agent-visible
    __hip_atomic_fetch_add(&ctr[id], 1u, __ATOMIC_RELAXED, __HIP_MEMORY_SCOPE_AGENT);
    while (__hip_atomic_load(&ctr[id], __ATOMIC_RELAXED, __HIP_MEMORY_SCOPE_AGENT) < 256u) {
      __builtin_amdgcn_s_sleep(2);
    }
    __threadfence();  // acquire: see all other blocks' writes
  }
  __syncthreads();
}

// ---------------- init: weight folds ----------------
__global__ __launch_bounds__(256) void k_init(
    const float* __restrict__ Wp, const float* __restrict__ Wg,
    float* __restrict__ Wpf, float* __restrict__ Wg2f) {
  int i = blockIdx.x * 256 + threadIdx.x;
  if (i < 1024 * 512) {
    int n = i >> 9, k = i & 511;
    Wpf[i] = Wp[(size_t)n * 1024 + k] + Wp[(size_t)n * 1024 + k + 512];
  }
  if (i < 1024 * 1024) {
    int j = i >> 10, kk = i & 1023;
    const float* wr = Wg + (size_t)(1024 + j) * 2048;
    Wg2f[i] = (kk < 512) ? (wr[kk] + wr[kk + 512]) : (wr[kk + 512] + wr[kk + 1024]);
  }
}

// ---------------- zero barrier counters ----------------
__global__ __launch_bounds__(256) void k_zero(unsigned* __restrict__ ctr) {
  int i = blockIdx.x * 256 + threadIdx.x;
  if (i < 2048) ctr[i] = 0u;
}

// ---------------- WUq = uq @ Wqf.T : [8192,512] x [512,1024] ----------------
__global__ __launch_bounds__(256) void k_wuq(
    const float* __restrict__ A, const float* __restrict__ Wq, float* __restrict__ C) {
  __shared__ float As[16][65];
  __shared__ float Bs[16][65];
  int bm = blockIdx.x * 64, bn = blockIdx.y * 64;
  int t = threadIdx.x;
  int tx = t & 15, ty = t >> 4;
  float acc[4][4] = {};
  for (int k0 = 0; k0 < 512; k0 += 16) {
#pragma unroll
    for (int l = 0; l < 4; ++l) {
      int idx = t + l * 256;
      int row = idx >> 4, kk = idx & 15;
      As[kk][row] = A[(size_t)(bm + row) * 512 + k0 + kk];
      Bs[kk][row] = Wq[(size_t)(bn + row) * 1024 + k0 + kk] +
                    Wq[(size_t)(bn + row) * 1024 + k0 + kk + 512];
    }
    __syncthreads();
#pragma unroll
    for (int kk = 0; kk < 16; ++kk) {
      float a0[4], b0[4];
#pragma unroll
      for (int i = 0; i < 4; ++i) a0[i] = As[kk][ty * 4 + i];
#pragma unroll
      for (int j = 0; j < 4; ++j) b0[j] = Bs[kk][tx * 4 + j];
#pragma unroll
      for (int i = 0; i < 4; ++i)
#pragma unroll
        for (int j = 0; j < 4; ++j) acc[i][j] += a0[i] * b0[j];
    }
    __syncthreads();
  }
#pragma unroll
  for (int i = 0; i < 4; ++i)
#pragma unroll
    for (int j = 0; j < 4; ++j)
      C[(size_t)(bm + ty * 4 + i) * 1024 + bn + tx * 4 + j] = acc[i][j];
}

// ---------------- persistent scan kernel ----------------
__global__ __launch_bounds__(256, 1) void k_scan(
    const float* __restrict__ up, const float* __restrict__ uq,
    const float* __restrict__ v0, const float* __restrict__ Vvec,
    const float* __restrict__ Wv, const float* __restrict__ W_hh,
    const float* __restrict__ b_hh, const float* __restrict__ W_ih,
    const float* __restrict__ b_ih, const float* __restrict__ Wpf,
    const float* __restrict__ Wg2f, const float* __restrict__ WUq,
    float* __restrict__ tbuf, float* __restrict__ gh0, float* __restrict__ gh1,
    float* __restrict__ sbuf, float* __restrict__ rhalf, float* __restrict__ cbuf,
    float* __restrict__ gibuf, float* __restrict__ out, unsigned* __restrict__ ctr) {
  const int blk = blockIdx.x, tid = threadIdx.x;
  const int lane = tid & 63, wave = tid >> 6;
  const int s = blk & 63, bg = blk >> 6, b0 = bg * 8;
  __shared__ float vnew[8][H];   // 32 KB: this bgroup's v-state, persists all steps
  __shared__ float upb[8][512];  // 16 KB
  __shared__ float a_s[256];
  __shared__ float red[4];

  for (int p = 0; p < 256; ++p) {
    float* ghn = (p & 1) ? gh1 : gh0;
    float* gho = (p & 1) ? gh0 : gh1;
    const int bid = p * 5;

    // ---- Phase A: GRU finish of step p-1 (in LDS), then t/gh GEMV ----
    if (p == 0) {
      for (int bb = 0; bb < 8; ++bb)
#pragma unroll
        for (int ii = 0; ii < 4; ++ii) {
          int h = tid + ii * 256;
          vnew[bb][h] = v0[(size_t)(b0 + bb) * H + h];
        }
    } else {
      for (int bb = 0; bb < 8; ++bb) {
        int b = b0 + bb;
        const float* gib = gibuf + (size_t)b * H3;
        const float* ghb = gho + (size_t)b * H3;
#pragma unroll
        for (int ii = 0; ii < 4; ++ii) {
          int h = tid + ii * 256;
          float rg = fsig(gib[h] + ghb[h]);
          float z = fsig(gib[H + h] + ghb[H + h]);
          float nn = ftanh(gib[2 * H + h] + rg * ghb[2 * H + h]);
          float vn = (1.0f - z) * nn + z * vnew[bb][h];
          vnew[bb][h] = vn;
          if (s == 0) out[((size_t)(p - 1) * NB + b) * H + h] = vn;
        }
      }
    }
    const bool is_t = (s < 16);
    if (is_t) {
      for (int idx = tid; idx < 8 * 512; idx += 256) {
        int bb = idx >> 9, k = idx & 511;
        upb[bb][k] = up[((size_t)p * NB + (b0 + bb)) * 512 + k];
      }
    }
    __syncthreads();

    {
      float vreg[8][16];
#pragma unroll
      for (int bb = 0; bb < 8; ++bb)
#pragma unroll
        for (int i = 0; i < 16; ++i) vreg[bb][i] = vnew[bb][lane + i * 64];

      int n0 = s * 64 + wave * 16;
      for (int rr = 0; rr < 16; ++rr) {
        int n = n0 + rr;
        float acc[8];
#pragma unroll
        for (int bb = 0; bb < 8; ++bb) acc[bb] = 0.0f;
        if (is_t) {
          const float* wr = Wv + (size_t)n * H;
#pragma unroll
          for (int i = 0; i < 16; ++i) {
            float w = wr[lane + i * 64];
#pragma unroll
            for (int bb = 0; bb < 8; ++bb) acc[bb] = fmaf(w, vreg[bb][i], acc[bb]);
          }
          const float* wp = Wpf + (size_t)n * 512;
#pragma unroll
          for (int i = 0; i < 8; ++i) {
            float w = wp[lane + i * 64];
#pragma unroll
            for (int bb = 0; bb < 8; ++bb) acc[bb] = fmaf(w, upb[bb][lane + i * 64], acc[bb]);
          }
#pragma unroll
          for (int bb = 0; bb < 8; ++bb) {
            float a = acc[bb];
#pragma unroll
            for (int o = 32; o >= 1; o >>= 1) a += __shfl_xor(a, o, 64);
            if (lane == 0) tbuf[(size_t)(b0 + bb) * H + n] = a;
          }
        } else {
          int m = n - H;
          const float* wr = W_hh + (size_t)m * H;
#pragma unroll
          for (int i = 0; i < 16; ++i) {
            float w = wr[lane + i * 64];
#pragma unroll
            for (int bb = 0; bb < 8; ++bb) acc[bb] = fmaf(w, vreg[bb][i], acc[bb]);
          }
          float bias = b_hh[m];
#pragma unroll
          for (int bb = 0; bb < 8; ++bb) {
            float a = acc[bb];
#pragma unroll
            for (int o = 32; o >= 1; o >>= 1) a += __shfl_xor(a, o, 64);
            if (lane == 0) ghn[(size_t)(b0 + bb) * H3 + m] = a + bias;
          }
        }
      }
    }
    gbar(ctr, bid + 0);

    // ---- Phase B: s[b][q] = sum_h tanh(t+WUq)*Vvec; prep rhalf ----
    {
      if (blk < NB) {
        int b = blk;
        float* rb = rhalf + (size_t)b * 1024;
        const float* ub = up + ((size_t)p * NB + b) * 512;
        rb[tid] = ub[tid];
        rb[tid + 256] = ub[tid + 256];
        rb[512 + tid] = 0.0f;
        rb[768 + tid] = 0.0f;
      }
      int q = blk;
      const float* wqb = WUq + (size_t)q * NB * H;
      for (int r = 0; r < 8; ++r) {
        int b = wave * 8 + r;
        const float* wq = wqb + (size_t)b * H;
        const float* tb = tbuf + (size_t)b * H;
        const float* vv = Vvec + (size_t)b * H;
        float a = 0.0f;
#pragma unroll
        for (int i = 0; i < 16; ++i) {
          int h = lane + i * 64;
          a += ftanh(tb[h] + wq[h]) * vv[h];
        }
#pragma unroll
        for (int o = 32; o >= 1; o >>= 1) a += __shfl_xor(a, o, 64);
        if (lane == 0) sbuf[b * LQn + q] = a;
      }
    }
    gbar(ctr, bid + 1);

    // ---- Phase C: softmax (redundant per q-slice) + partial c via atomics ----
    {
      int b = blk & 31, qs = blk >> 5;
      float sv = sbuf[b * LQn + tid];
      float m = sv;
#pragma unroll
      for (int o = 32; o >= 1; o >>= 1) m = fmaxf(m, __shfl_xor(m, o, 64));
      if (lane == 0) red[wave] = m;
      __syncthreads();
      float bm = fmaxf(fmaxf(red[0], red[1]), fmaxf(red[2], red[3]));
      __syncthreads();
      float e = __expf(sv - bm);
      float se = e;
#pragma unroll
      for (int o = 32; o >= 1; o >>= 1) se += __shfl_xor(se, o, 64);
      if (lane == 0) red[wave] = se;
      __syncthreads();
      float tot = red[0] + red[1] + red[2] + red[3];
      a_s[tid] = e / tot;
      __syncthreads();
      int q0 = qs * 32;
      float acc0 = 0.0f, acc1 = 0.0f;
#pragma unroll 8
      for (int qq = 0; qq < 32; ++qq) {
        float a = a_s[q0 + qq];
        const float* uqr = uq + ((size_t)(q0 + qq) * NB + b) * 512;
        acc0 = fmaf(a, uqr[tid], acc0);
        acc1 = fmaf(a, uqr[tid + 256], acc1);
      }
      atomicAdd(&rhalf[(size_t)b * 1024 + 512 + tid], acc0);
      atomicAdd(&rhalf[(size_t)b * 1024 + 768 + tid], acc1);
    }
    gbar(ctr, bid + 2);

    // ---- Phase D: c_ = sig(rhalf @ Wg2f.T) * c ----
    {
      float rreg[16];
      int j0 = s * 16 + wave * 4;
      float accs[4][8];
#pragma unroll
      for (int rr = 0; rr < 4; ++rr)
#pragma unroll
        for (int bb = 0; bb < 8; ++bb) accs[rr][bb] = 0.0f;
      for (int bb = 0; bb < 8; ++bb) {
#pragma unroll
        for (int i = 0; i < 16; ++i)
          rreg[i] = rhalf[(size_t)(b0 + bb) * 1024 + lane + i * 64];
#pragma unroll
        for (int rr = 0; rr < 4; ++rr) {
          const float* wr = Wg2f + (size_t)(j0 + rr) * 1024;
          float a = 0.0f;
#pragma unroll
          for (int i = 0; i < 16; ++i) a = fmaf(wr[lane + i * 64], rreg[i], a);
          accs[rr][bb] = a;
        }
      }
#pragma unroll
      for (int rr = 0; rr < 4; ++rr) {
        int j = j0 + rr;
#pragma unroll
        for (int bb = 0; bb < 8; ++bb) {
          float a = accs[rr][bb];
#pragma unroll
          for (int o = 32; o >= 1; o >>= 1) a += __shfl_xor(a, o, 64);
          if (lane == 0) {
            float cv = rhalf[(size_t)(b0 + bb) * 1024 + 512 + (j & 511)];
            cbuf[(size_t)(b0 + bb) * 1024 + j] = fsig(a) * cv;
          }
        }
      }
    }
    gbar(ctr, bid + 3);

    // ---- Phase E: gi = c_ @ W_ih.T + b_ih ----
    {
      float creg[8][16];
#pragma unroll
      for (int bb = 0; bb < 8; ++bb)
#pragma unroll
        for (int i = 0; i < 16; ++i)
          creg[bb][i] = cbuf[(size_t)(b0 + bb) * 1024 + lane + i * 64];
      int r0 = s * 48 + wave * 12;
      for (int rr = 0; rr < 12; ++rr) {
        int r = r0 + rr;
        const float* wr = W_ih + (size_t)r * 1024;
        float acc[8];
#pragma unroll
        for (int bb = 0; bb < 8; ++bb) acc[bb] = 0.0f;
#pragma unroll
        for (int i = 0; i < 16; ++i) {
          float w = wr[lane + i * 64];
#pragma unroll
          for (int bb = 0; bb < 8; ++bb) acc[bb] = fmaf(w, creg[bb][i], acc[bb]);
        }
        float bias = b_ih[r];
#pragma unroll
        for (int bb = 0; bb < 8; ++bb) {
          float a = acc[bb];
#pragma unroll
          for (int o = 32; o >= 1; o >>= 1) a += __shfl_xor(a, o, 64);
          if (lane == 0) gibuf[(size_t)(b0 + bb) * H3 + r] = a + bias;
        }
      }
    }
    gbar(ctr, bid + 4);
  }

  // ---- final GRU for step 255 ----
  if (tid < 128) {
    int bb = tid >> 4;
    int h = s * 16 + (tid & 15);
    int b = b0 + bb;
    const float* gib = gibuf + (size_t)b * H3;
    const float* ghb = gh1 + (size_t)b * H3;
    float rg = fsig(gib[h] + ghb[h]);
    float z = fsig(gib[H + h] + ghb[H + h]);
    float nn = ftanh(gib[2 * H + h] + rg * ghb[2 * H + h]);
    float vn = (1.0f - z) * nn + z * vnew[bb][h];
    out[((size_t)255 * NB + b) * H + h] = vn;
  }
}

extern "C" void kernel_launch(void* const* d_in, const int* in_sizes, int n_in,
                              void* d_out, int out_size, void* d_ws, size_t ws_size,
                              hipStream_t stream) {
  const float* up = (const float*)d_in[0];
  const float* uq = (const float*)d_in[1];
  const float* v0 = (const float*)d_in[2];
  const float* Vvec = (const float*)d_in[3];
  const float* Wp = (const float*)d_in[4];
  const float* Wq = (const float*)d_in[5];
  const float* Wv = (const float*)d_in[6];
  const float* Wg = (const float*)d_in[7];
  const float* W_ih = (const float*)d_in[8];
  const float* W_hh = (const float*)d_in[9];
  const float* b_ih = (const float*)d_in[10];
  const float* b_hh = (const float*)d_in[11];
  float* out = (float*)d_out;
  float* ws = (float*)d_ws;

  float* tbuf = ws;                    // 32768
  float* gh0 = ws + 32768;             // 98304
  float* gh1 = ws + 131072;            // 98304
  float* sbuf = ws + 229376;           // 8192
  float* rhalf = ws + 237568;          // 32768
  float* cbuf = ws + 270336;           // 32768
  float* gibuf = ws + 303104;          // 98304
  float* Wpf = ws + 401408;            // 524288
  float* Wg2f = ws + 925696;           // 1048576
  float* WUq = ws + 1974272;           // 8388608
  unsigned* ctr = (unsigned*)(ws + 10362880);  // 2048 uints

  k_init<<<4096, 256, 0, stream>>>(Wp, Wg, Wpf, Wg2f);
  k_zero<<<8, 256, 0, stream>>>(ctr);
  k_wuq<<<dim3(128, 16), 256, 0, stream>>>(uq, Wq, WUq);
  k_scan<<<256, 256, 0, stream>>>(up, uq, v0, Vvec, Wv, W_hh, b_hh, W_ih, b_ih,
                                  Wpf, Wg2f, WUq, tbuf, gh0, gh1, sbuf, rhalf,
                                  cbuf, gibuf, out, ctr);
}

// Round 3
// 62174.579 us; speedup vs baseline: 1.1797x; 1.1797x over previous
//
#include <hip/hip_runtime.h>

// PQMatcher persistent-kernel v2.
// Round-3 change: barrier redesign. Round-2's flat barrier (one cacheline for
// both arrival RMWs and 255 spinning pollers) measured ~50us/barrier -> 65ms.
// New barrier: tree arrival (8 sub-lines x 32 blocks + 1 root line) with
// release on 8 SEPARATE cachelines (32 pollers each). Arrival lines are never
// polled; release lines are written once. Phase A uses a split-phase barrier:
// gh-blocks arrive before computing gh (gh only consumed after bar4), so bar0
// is gated only by the 64 t-blocks.

#define NB 32
#define H 1024
#define H3 3072
#define LQn 256

__device__ __forceinline__ float fsig(float x) { return 1.0f / (1.0f + __expf(-x)); }
__device__ __forceinline__ float ftanh(float x) { return 1.0f - 2.0f / (1.0f + __expf(2.0f * x)); }

// ---- barrier: per-id layout = arr[8 lines] | root[1 line] | rel[8 lines] ----
#define BAR_STRIDE 272  // uints: 8*16 + 16 + 8*16
#define N_BAR 1280      // 256 steps * 5

__device__ __forceinline__ void gbar_arrive(unsigned* __restrict__ ctr, int id, int blk) {
  __syncthreads();  // all waves' prior stores drained (compiler waitcnt before barrier)
  if (threadIdx.x == 0) {
    unsigned* base = ctr + (size_t)id * BAR_STRIDE;
    __threadfence();  // release: flush this XCD's dirty L2 past coherence point
    unsigned o = __hip_atomic_fetch_add(base + (blk & 7) * 16, 1u,
                                        __ATOMIC_RELAXED, __HIP_MEMORY_SCOPE_AGENT);
    if (o == 31u) {
      unsigned r = __hip_atomic_fetch_add(base + 128, 1u,
                                          __ATOMIC_RELAXED, __HIP_MEMORY_SCOPE_AGENT);
      if (r == 7u) {
#pragma unroll
        for (int l = 0; l < 8; ++l)
          __hip_atomic_store(base + 144 + l * 16, 1u,
                             __ATOMIC_RELAXED, __HIP_MEMORY_SCOPE_AGENT);
      }
    }
  }
}

__device__ __forceinline__ void gbar_wait(unsigned* __restrict__ ctr, int id, int blk) {
  if (threadIdx.x == 0) {
    unsigned* my = ctr + (size_t)id * BAR_STRIDE + 144 + (blk >> 5) * 16;
    while (__hip_atomic_load(my, __ATOMIC_RELAXED, __HIP_MEMORY_SCOPE_AGENT) == 0u)
      __builtin_amdgcn_s_sleep(2);
    __threadfence();  // acquire: invalidate stale cached lines
  }
  __syncthreads();
}

__device__ __forceinline__ void gbar(unsigned* __restrict__ ctr, int id, int blk) {
  gbar_arrive(ctr, id, blk);
  gbar_wait(ctr, id, blk);
}

// ---------------- init: weight folds ----------------
__global__ __launch_bounds__(256) void k_init(
    const float* __restrict__ Wp, const float* __restrict__ Wg,
    float* __restrict__ Wpf, float* __restrict__ Wg2f) {
  int i = blockIdx.x * 256 + threadIdx.x;
  if (i < 1024 * 512) {
    int n = i >> 9, k = i & 511;
    Wpf[i] = Wp[(size_t)n * 1024 + k] + Wp[(size_t)n * 1024 + k + 512];
  }
  if (i < 1024 * 1024) {
    int j = i >> 10, kk = i & 1023;
    const float* wr = Wg + (size_t)(1024 + j) * 2048;
    Wg2f[i] = (kk < 512) ? (wr[kk] + wr[kk + 512]) : (wr[kk + 512] + wr[kk + 1024]);
  }
}

// ---------------- zero barrier counters ----------------
__global__ __launch_bounds__(256) void k_zero(unsigned* __restrict__ ctr) {
  int i = blockIdx.x * 256 + threadIdx.x;
  if (i < N_BAR * BAR_STRIDE) ctr[i] = 0u;
}

// ---------------- WUq = uq @ Wqf.T : [8192,512] x [512,1024] ----------------
__global__ __launch_bounds__(256) void k_wuq(
    const float* __restrict__ A, const float* __restrict__ Wq, float* __restrict__ C) {
  __shared__ float As[16][65];
  __shared__ float Bs[16][65];
  int bm = blockIdx.x * 64, bn = blockIdx.y * 64;
  int t = threadIdx.x;
  int tx = t & 15, ty = t >> 4;
  float acc[4][4] = {};
  for (int k0 = 0; k0 < 512; k0 += 16) {
#pragma unroll
    for (int l = 0; l < 4; ++l) {
      int idx = t + l * 256;
      int row = idx >> 4, kk = idx & 15;
      As[kk][row] = A[(size_t)(bm + row) * 512 + k0 + kk];
      Bs[kk][row] = Wq[(size_t)(bn + row) * 1024 + k0 + kk] +
                    Wq[(size_t)(bn + row) * 1024 + k0 + kk + 512];
    }
    __syncthreads();
#pragma unroll
    for (int kk = 0; kk < 16; ++kk) {
      float a0[4], b0[4];
#pragma unroll
      for (int i = 0; i < 4; ++i) a0[i] = As[kk][ty * 4 + i];
#pragma unroll
      for (int j = 0; j < 4; ++j) b0[j] = Bs[kk][tx * 4 + j];
#pragma unroll
      for (int i = 0; i < 4; ++i)
#pragma unroll
        for (int j = 0; j < 4; ++j) acc[i][j] += a0[i] * b0[j];
    }
    __syncthreads();
  }
#pragma unroll
  for (int i = 0; i < 4; ++i)
#pragma unroll
    for (int j = 0; j < 4; ++j)
      C[(size_t)(bm + ty * 4 + i) * 1024 + bn + tx * 4 + j] = acc[i][j];
}

// ---------------- persistent scan kernel ----------------
__global__ __launch_bounds__(256, 1) void k_scan(
    const float* __restrict__ up, const float* __restrict__ uq,
    const float* __restrict__ v0, const float* __restrict__ Vvec,
    const float* __restrict__ Wv, const float* __restrict__ W_hh,
    const float* __restrict__ b_hh, const float* __restrict__ W_ih,
    const float* __restrict__ b_ih, const float* __restrict__ Wpf,
    const float* __restrict__ Wg2f, const float* __restrict__ WUq,
    float* __restrict__ tbuf, float* __restrict__ gh0, float* __restrict__ gh1,
    float* __restrict__ sbuf, float* __restrict__ rhalf, float* __restrict__ cbuf,
    float* __restrict__ gibuf, float* __restrict__ out, unsigned* __restrict__ ctr) {
  const int blk = blockIdx.x, tid = threadIdx.x;
  const int lane = tid & 63, wave = tid >> 6;
  const int s = blk & 63, bg = blk >> 6, b0 = bg * 8;
  __shared__ float vnew[8][H];   // 32 KB: this bgroup's v-state, persists all steps
  __shared__ float upb[8][512];  // 16 KB
  __shared__ float a_s[256];
  __shared__ float red[4];

  for (int p = 0; p < 256; ++p) {
    float* ghn = (p & 1) ? gh1 : gh0;
    float* gho = (p & 1) ? gh0 : gh1;
    const int bid = p * 5;

    // ---- Phase A: GRU finish of step p-1 (in LDS), then t/gh GEMV ----
    if (p == 0) {
      for (int bb = 0; bb < 8; ++bb)
#pragma unroll
        for (int ii = 0; ii < 4; ++ii) {
          int h = tid + ii * 256;
          vnew[bb][h] = v0[(size_t)(b0 + bb) * H + h];
        }
    } else {
      for (int bb = 0; bb < 8; ++bb) {
        int b = b0 + bb;
        const float* gib = gibuf + (size_t)b * H3;
        const float* ghb = gho + (size_t)b * H3;
#pragma unroll
        for (int ii = 0; ii < 4; ++ii) {
          int h = tid + ii * 256;
          float rg = fsig(gib[h] + ghb[h]);
          float z = fsig(gib[H + h] + ghb[H + h]);
          float nn = ftanh(gib[2 * H + h] + rg * ghb[2 * H + h]);
          float vn = (1.0f - z) * nn + z * vnew[bb][h];
          vnew[bb][h] = vn;
          if (s == 0) out[((size_t)(p - 1) * NB + b) * H + h] = vn;
        }
      }
    }
    const bool is_t = (s < 16);
    if (is_t) {
      for (int idx = tid; idx < 8 * 512; idx += 256) {
        int bb = idx >> 9, k = idx & 511;
        upb[bb][k] = up[((size_t)p * NB + (b0 + bb)) * 512 + k];
      }
    }
    __syncthreads();

    {
      float vreg[8][16];
#pragma unroll
      for (int bb = 0; bb < 8; ++bb)
#pragma unroll
        for (int i = 0; i < 16; ++i) vreg[bb][i] = vnew[bb][lane + i * 64];

      int n0 = s * 64 + wave * 16;
      if (is_t) {
        // t gates phase B: compute, then arrive.
        for (int rr = 0; rr < 16; ++rr) {
          int n = n0 + rr;
          float acc[8];
#pragma unroll
          for (int bb = 0; bb < 8; ++bb) acc[bb] = 0.0f;
          const float* wr = Wv + (size_t)n * H;
#pragma unroll
          for (int i = 0; i < 16; ++i) {
            float w = wr[lane + i * 64];
#pragma unroll
            for (int bb = 0; bb < 8; ++bb) acc[bb] = fmaf(w, vreg[bb][i], acc[bb]);
          }
          const float* wp = Wpf + (size_t)n * 512;
#pragma unroll
          for (int i = 0; i < 8; ++i) {
            float w = wp[lane + i * 64];
#pragma unroll
            for (int bb = 0; bb < 8; ++bb) acc[bb] = fmaf(w, upb[bb][lane + i * 64], acc[bb]);
          }
#pragma unroll
          for (int bb = 0; bb < 8; ++bb) {
            float a = acc[bb];
#pragma unroll
            for (int o = 32; o >= 1; o >>= 1) a += __shfl_xor(a, o, 64);
            if (lane == 0) tbuf[(size_t)(b0 + bb) * H + n] = a;
          }
        }
        gbar_arrive(ctr, bid + 0, blk);
        gbar_wait(ctr, bid + 0, blk);
      } else {
        // gh not needed until after bar4: arrive first, compute while others wait.
        gbar_arrive(ctr, bid + 0, blk);
        for (int rr = 0; rr < 16; ++rr) {
          int m = n0 + rr - H;
          float acc[8];
#pragma unroll
          for (int bb = 0; bb < 8; ++bb) acc[bb] = 0.0f;
          const float* wr = W_hh + (size_t)m * H;
#pragma unroll
          for (int i = 0; i < 16; ++i) {
            float w = wr[lane + i * 64];
#pragma unroll
            for (int bb = 0; bb < 8; ++bb) acc[bb] = fmaf(w, vreg[bb][i], acc[bb]);
          }
          float bias = b_hh[m];
#pragma unroll
          for (int bb = 0; bb < 8; ++bb) {
            float a = acc[bb];
#pragma unroll
            for (int o = 32; o >= 1; o >>= 1) a += __shfl_xor(a, o, 64);
            if (lane == 0) ghn[(size_t)(b0 + bb) * H3 + m] = a + bias;
          }
        }
        gbar_wait(ctr, bid + 0, blk);
      }
    }

    // ---- Phase B: s[b][q] = sum_h tanh(t+WUq)*Vvec; prep rhalf ----
    {
      if (blk < NB) {
        int b = blk;
        float* rb = rhalf + (size_t)b * 1024;
        const float* ub = up + ((size_t)p * NB + b) * 512;
        rb[tid] = ub[tid];
        rb[tid + 256] = ub[tid + 256];
        rb[512 + tid] = 0.0f;
        rb[768 + tid] = 0.0f;
      }
      int q = blk;
      const float* wqb = WUq + (size_t)q * NB * H;
      for (int r = 0; r < 8; ++r) {
        int b = wave * 8 + r;
        const float* wq = wqb + (size_t)b * H;
        const float* tb = tbuf + (size_t)b * H;
        const float* vv = Vvec + (size_t)b * H;
        float a = 0.0f;
#pragma unroll
        for (int i = 0; i < 16; ++i) {
          int h = lane + i * 64;
          a += ftanh(tb[h] + wq[h]) * vv[h];
        }
#pragma unroll
        for (int o = 32; o >= 1; o >>= 1) a += __shfl_xor(a, o, 64);
        if (lane == 0) sbuf[b * LQn + q] = a;
      }
    }
    gbar(ctr, bid + 1, blk);

    // ---- Phase C: softmax (redundant per q-slice) + partial c via atomics ----
    {
      int b = blk & 31, qs = blk >> 5;
      float sv = sbuf[b * LQn + tid];
      float m = sv;
#pragma unroll
      for (int o = 32; o >= 1; o >>= 1) m = fmaxf(m, __shfl_xor(m, o, 64));
      if (lane == 0) red[wave] = m;
      __syncthreads();
      float bm = fmaxf(fmaxf(red[0], red[1]), fmaxf(red[2], red[3]));
      __syncthreads();
      float e = __expf(sv - bm);
      float se = e;
#pragma unroll
      for (int o = 32; o >= 1; o >>= 1) se += __shfl_xor(se, o, 64);
      if (lane == 0) red[wave] = se;
      __syncthreads();
      float tot = red[0] + red[1] + red[2] + red[3];
      a_s[tid] = e / tot;
      __syncthreads();
      int q0 = qs * 32;
      float acc0 = 0.0f, acc1 = 0.0f;
#pragma unroll 8
      for (int qq = 0; qq < 32; ++qq) {
        float a = a_s[q0 + qq];
        const float* uqr = uq + ((size_t)(q0 + qq) * NB + b) * 512;
        acc0 = fmaf(a, uqr[tid], acc0);
        acc1 = fmaf(a, uqr[tid + 256], acc1);
      }
      atomicAdd(&rhalf[(size_t)b * 1024 + 512 + tid], acc0);
      atomicAdd(&rhalf[(size_t)b * 1024 + 768 + tid], acc1);
    }
    gbar(ctr, bid + 2, blk);

    // ---- Phase D: c_ = sig(rhalf @ Wg2f.T) * c ----
    {
      float rreg[16];
      int j0 = s * 16 + wave * 4;
      float accs[4][8];
#pragma unroll
      for (int rr = 0; rr < 4; ++rr)
#pragma unroll
        for (int bb = 0; bb < 8; ++bb) accs[rr][bb] = 0.0f;
      for (int bb = 0; bb < 8; ++bb) {
#pragma unroll
        for (int i = 0; i < 16; ++i)
          rreg[i] = rhalf[(size_t)(b0 + bb) * 1024 + lane + i * 64];
#pragma unroll
        for (int rr = 0; rr < 4; ++rr) {
          const float* wr = Wg2f + (size_t)(j0 + rr) * 1024;
          float a = 0.0f;
#pragma unroll
          for (int i = 0; i < 16; ++i) a = fmaf(wr[lane + i * 64], rreg[i], a);
          accs[rr][bb] = a;
        }
      }
#pragma unroll
      for (int rr = 0; rr < 4; ++rr) {
        int j = j0 + rr;
#pragma unroll
        for (int bb = 0; bb < 8; ++bb) {
          float a = accs[rr][bb];
#pragma unroll
          for (int o = 32; o >= 1; o >>= 1) a += __shfl_xor(a, o, 64);
          if (lane == 0) {
            float cv = rhalf[(size_t)(b0 + bb) * 1024 + 512 + (j & 511)];
            cbuf[(size_t)(b0 + bb) * 1024 + j] = fsig(a) * cv;
          }
        }
      }
    }
    gbar(ctr, bid + 3, blk);

    // ---- Phase E: gi = c_ @ W_ih.T + b_ih ----
    {
      float creg[8][16];
#pragma unroll
      for (int bb = 0; bb < 8; ++bb)
#pragma unroll
        for (int i = 0; i < 16; ++i)
          creg[bb][i] = cbuf[(size_t)(b0 + bb) * 1024 + lane + i * 64];
      int r0 = s * 48 + wave * 12;
      for (int rr = 0; rr < 12; ++rr) {
        int r = r0 + rr;
        const float* wr = W_ih + (size_t)r * 1024;
        float acc[8];
#pragma unroll
        for (int bb = 0; bb < 8; ++bb) acc[bb] = 0.0f;
#pragma unroll
        for (int i = 0; i < 16; ++i) {
          float w = wr[lane + i * 64];
#pragma unroll
          for (int bb = 0; bb < 8; ++bb) acc[bb] = fmaf(w, creg[bb][i], acc[bb]);
        }
        float bias = b_ih[r];
#pragma unroll
        for (int bb = 0; bb < 8; ++bb) {
          float a = acc[bb];
#pragma unroll
          for (int o = 32; o >= 1; o >>= 1) a += __shfl_xor(a, o, 64);
          if (lane == 0) gibuf[(size_t)(b0 + bb) * H3 + r] = a + bias;
        }
      }
    }
    gbar(ctr, bid + 4, blk);
  }

  // ---- final GRU for step 255 ----
  if (tid < 128) {
    int bb = tid >> 4;
    int h = s * 16 + (tid & 15);
    int b = b0 + bb;
    const float* gib = gibuf + (size_t)b * H3;
    const float* ghb = gh1 + (size_t)b * H3;
    float rg = fsig(gib[h] + ghb[h]);
    float z = fsig(gib[H + h] + ghb[H + h]);
    float nn = ftanh(gib[2 * H + h] + rg * ghb[2 * H + h]);
    float vn = (1.0f - z) * nn + z * vnew[bb][h];
    out[((size_t)255 * NB + b) * H + h] = vn;
  }
}

extern "C" void kernel_launch(void* const* d_in, const int* in_sizes, int n_in,
                              void* d_out, int out_size, void* d_ws, size_t ws_size,
                              hipStream_t stream) {
  const float* up = (const float*)d_in[0];
  const float* uq = (const float*)d_in[1];
  const float* v0 = (const float*)d_in[2];
  const float* Vvec = (const float*)d_in[3];
  const float* Wp = (const float*)d_in[4];
  const float* Wq = (const float*)d_in[5];
  const float* Wv = (const float*)d_in[6];
  const float* Wg = (const float*)d_in[7];
  const float* W_ih = (const float*)d_in[8];
  const float* W_hh = (const float*)d_in[9];
  const float* b_ih = (const float*)d_in[10];
  const float* b_hh = (const float*)d_in[11];
  float* out = (float*)d_out;
  float* ws = (float*)d_ws;

  float* tbuf = ws;                    // 32768
  float* gh0 = ws + 32768;             // 98304
  float* gh1 = ws + 131072;            // 98304
  float* sbuf = ws + 229376;           // 8192
  float* rhalf = ws + 237568;          // 32768
  float* cbuf = ws + 270336;           // 32768
  float* gibuf = ws + 303104;          // 98304
  float* Wpf = ws + 401408;            // 524288
  float* Wg2f = ws + 925696;           // 1048576
  float* WUq = ws + 1974272;           // 8388608
  unsigned* ctr = (unsigned*)(ws + 10362880);  // 1280*272 uints = 1.36 MB

  k_init<<<4096, 256, 0, stream>>>(Wp, Wg, Wpf, Wg2f);
  k_zero<<<1360, 256, 0, stream>>>(ctr);
  k_wuq<<<dim3(128, 16), 256, 0, stream>>>(uq, Wq, WUq);
  k_scan<<<256, 256, 0, stream>>>(up, uq, v0, Vvec, Wv, W_hh, b_hh, W_ih, b_ih,
                                  Wpf, Wg2f, WUq, tbuf, gh0, gh1, sbuf, rhalf,
                                  cbuf, gibuf, out, ctr);
}

// Round 4
// 56725.372 us; speedup vs baseline: 1.2931x; 1.0961x over previous
//
#include <hip/hip_runtime.h>

// PQMatcher persistent-kernel v3 — FENCE-FREE coherence.
// R3 post-mortem: the ~44us/barrier was NOT atomic contention (tree barrier
// changed nothing). It was __threadfence(): agent-scope fence on gfx950 =
// buffer_wbl2 + buffer_inv (full per-XCD L2 writeback + invalidate), issued by
// all 256 blocks at all 1280 barriers — and it also destroyed weight L2
// residency (12 GB HBM re-fetch).
// v3: ALL cross-block data moves via relaxed agent-scope atomic ld/st (sc1 ->
// served at L3 coherence point, bypasses L1/L2). No fences anywhere. Ordering:
// __syncthreads emits s_waitcnt vmcnt(0) before s_barrier, so sc1 data stores
// are complete at L3 before the (L3) arrival RMW issues. Weights stay normal
// cached loads -> L2-resident across steps.

#define NB 32
#define H 1024
#define H3 3072
#define LQn 256

__device__ __forceinline__ float fsig(float x) { return 1.0f / (1.0f + __expf(-x)); }
__device__ __forceinline__ float ftanh(float x) { return 1.0f - 2.0f / (1.0f + __expf(2.0f * x)); }

// Cross-block (coherent, L3-direct) accessors — no fences needed.
__device__ __forceinline__ float gld(const float* p) {
  return __hip_atomic_load(p, __ATOMIC_RELAXED, __HIP_MEMORY_SCOPE_AGENT);
}
__device__ __forceinline__ void gst(float* p, float v) {
  __hip_atomic_store(p, v, __ATOMIC_RELAXED, __HIP_MEMORY_SCOPE_AGENT);
}

// ---- barrier: per-id layout = arr[8 lines] | root[1 line] | rel[8 lines] ----
#define BAR_STRIDE 272  // uints
#define N_BAR 1280      // 256 steps * 5

__device__ __forceinline__ void gbar_arrive(unsigned* __restrict__ ctr, int id, int blk) {
  __syncthreads();  // drains vmcnt(0): all sc1 data stores completed at L3
  if (threadIdx.x == 0) {
    unsigned* base = ctr + (size_t)id * BAR_STRIDE;
    unsigned o = __hip_atomic_fetch_add(base + (blk & 7) * 16, 1u,
                                        __ATOMIC_RELAXED, __HIP_MEMORY_SCOPE_AGENT);
    if (o == 31u) {
      unsigned r = __hip_atomic_fetch_add(base + 128, 1u,
                                          __ATOMIC_RELAXED, __HIP_MEMORY_SCOPE_AGENT);
      if (r == 7u) {
#pragma unroll
        for (int l = 0; l < 8; ++l)
          __hip_atomic_store(base + 144 + l * 16, 1u,
                             __ATOMIC_RELAXED, __HIP_MEMORY_SCOPE_AGENT);
      }
    }
  }
}

__device__ __forceinline__ void gbar_wait(unsigned* __restrict__ ctr, int id, int blk) {
  if (threadIdx.x == 0) {
    unsigned* my = ctr + (size_t)id * BAR_STRIDE + 144 + (blk >> 5) * 16;
    while (__hip_atomic_load(my, __ATOMIC_RELAXED, __HIP_MEMORY_SCOPE_AGENT) == 0u)
      __builtin_amdgcn_s_sleep(1);
  }
  __syncthreads();
}

__device__ __forceinline__ void gbar(unsigned* __restrict__ ctr, int id, int blk) {
  gbar_arrive(ctr, id, blk);
  gbar_wait(ctr, id, blk);
}

// ---------------- init: weight folds ----------------
__global__ __launch_bounds__(256) void k_init(
    const float* __restrict__ Wp, const float* __restrict__ Wg,
    float* __restrict__ Wpf, float* __restrict__ Wg2f) {
  int i = blockIdx.x * 256 + threadIdx.x;
  if (i < 1024 * 512) {
    int n = i >> 9, k = i & 511;
    Wpf[i] = Wp[(size_t)n * 1024 + k] + Wp[(size_t)n * 1024 + k + 512];
  }
  if (i < 1024 * 1024) {
    int j = i >> 10, kk = i & 1023;
    const float* wr = Wg + (size_t)(1024 + j) * 2048;
    Wg2f[i] = (kk < 512) ? (wr[kk] + wr[kk + 512]) : (wr[kk + 512] + wr[kk + 1024]);
  }
}

// ---------------- zero barrier counters ----------------
__global__ __launch_bounds__(256) void k_zero(unsigned* __restrict__ ctr) {
  int i = blockIdx.x * 256 + threadIdx.x;
  if (i < N_BAR * BAR_STRIDE) ctr[i] = 0u;
}

// ---------------- WUq = uq @ Wqf.T : [8192,512] x [512,1024] ----------------
__global__ __launch_bounds__(256) void k_wuq(
    const float* __restrict__ A, const float* __restrict__ Wq, float* __restrict__ C) {
  __shared__ float As[16][65];
  __shared__ float Bs[16][65];
  int bm = blockIdx.x * 64, bn = blockIdx.y * 64;
  int t = threadIdx.x;
  int tx = t & 15, ty = t >> 4;
  float acc[4][4] = {};
  for (int k0 = 0; k0 < 512; k0 += 16) {
#pragma unroll
    for (int l = 0; l < 4; ++l) {
      int idx = t + l * 256;
      int row = idx >> 4, kk = idx & 15;
      As[kk][row] = A[(size_t)(bm + row) * 512 + k0 + kk];
      Bs[kk][row] = Wq[(size_t)(bn + row) * 1024 + k0 + kk] +
                    Wq[(size_t)(bn + row) * 1024 + k0 + kk + 512];
    }
    __syncthreads();
#pragma unroll
    for (int kk = 0; kk < 16; ++kk) {
      float a0[4], b0[4];
#pragma unroll
      for (int i = 0; i < 4; ++i) a0[i] = As[kk][ty * 4 + i];
#pragma unroll
      for (int j = 0; j < 4; ++j) b0[j] = Bs[kk][tx * 4 + j];
#pragma unroll
      for (int i = 0; i < 4; ++i)
#pragma unroll
        for (int j = 0; j < 4; ++j) acc[i][j] += a0[i] * b0[j];
    }
    __syncthreads();
  }
#pragma unroll
  for (int i = 0; i < 4; ++i)
#pragma unroll
    for (int j = 0; j < 4; ++j)
      C[(size_t)(bm + ty * 4 + i) * 1024 + bn + tx * 4 + j] = acc[i][j];
}

// ---------------- persistent scan kernel ----------------
__global__ __launch_bounds__(256, 1) void k_scan(
    const float* __restrict__ up, const float* __restrict__ uq,
    const float* __restrict__ v0, const float* __restrict__ Vvec,
    const float* __restrict__ Wv, const float* __restrict__ W_hh,
    const float* __restrict__ b_hh, const float* __restrict__ W_ih,
    const float* __restrict__ b_ih, const float* __restrict__ Wpf,
    const float* __restrict__ Wg2f, const float* __restrict__ WUq,
    float* __restrict__ tbuf, float* __restrict__ gh0, float* __restrict__ gh1,
    float* __restrict__ sbuf, float* __restrict__ rhalf, float* __restrict__ cbuf,
    float* __restrict__ gibuf, float* __restrict__ out, unsigned* __restrict__ ctr) {
  const int blk = blockIdx.x, tid = threadIdx.x;
  const int lane = tid & 63, wave = tid >> 6;
  const int s = blk & 63, bg = blk >> 6, b0 = bg * 8;
  __shared__ float vnew[8][H];   // 32 KB: persistent v-state for this b-group
  __shared__ float rh_s[8][H];   // 32 KB: staging for phases D/E
  __shared__ float upb[8][512];  // 16 KB
  __shared__ float a_s[256];
  __shared__ float red[4];

  for (int p = 0; p < 256; ++p) {
    float* ghn = (p & 1) ? gh1 : gh0;
    float* gho = (p & 1) ? gh0 : gh1;
    const int bid = p * 5;

    // ---- Phase A: GRU finish of step p-1 (in LDS), then t/gh GEMV ----
    if (p == 0) {
      for (int bb = 0; bb < 8; ++bb)
#pragma unroll
        for (int ii = 0; ii < 4; ++ii) {
          int h = tid + ii * 256;
          vnew[bb][h] = v0[(size_t)(b0 + bb) * H + h];
        }
    } else {
      for (int bb = 0; bb < 8; ++bb) {
        int b = b0 + bb;
        const float* gib = gibuf + (size_t)b * H3;
        const float* ghb = gho + (size_t)b * H3;
#pragma unroll
        for (int ii = 0; ii < 4; ++ii) {
          int h = tid + ii * 256;
          float rg = fsig(gld(gib + h) + gld(ghb + h));
          float z = fsig(gld(gib + H + h) + gld(ghb + H + h));
          float nn = ftanh(gld(gib + 2 * H + h) + rg * gld(ghb + 2 * H + h));
          float vn = (1.0f - z) * nn + z * vnew[bb][h];
          vnew[bb][h] = vn;
          if (s == 0) out[((size_t)(p - 1) * NB + b) * H + h] = vn;
        }
      }
    }
    const bool is_t = (s < 16);
    if (is_t) {
      for (int idx = tid; idx < 8 * 512; idx += 256) {
        int bb = idx >> 9, k = idx & 511;
        upb[bb][k] = up[((size_t)p * NB + (b0 + bb)) * 512 + k];
      }
    }
    __syncthreads();

    {
      float vreg[8][16];
#pragma unroll
      for (int bb = 0; bb < 8; ++bb)
#pragma unroll
        for (int i = 0; i < 16; ++i) vreg[bb][i] = vnew[bb][lane + i * 64];

      int n0 = s * 64 + wave * 16;
      if (is_t) {
        // t gates phase B: compute, then arrive.
        for (int rr = 0; rr < 16; ++rr) {
          int n = n0 + rr;
          float acc[8];
#pragma unroll
          for (int bb = 0; bb < 8; ++bb) acc[bb] = 0.0f;
          const float* wr = Wv + (size_t)n * H;
#pragma unroll
          for (int i = 0; i < 16; ++i) {
            float w = wr[lane + i * 64];
#pragma unroll
            for (int bb = 0; bb < 8; ++bb) acc[bb] = fmaf(w, vreg[bb][i], acc[bb]);
          }
          const float* wp = Wpf + (size_t)n * 512;
#pragma unroll
          for (int i = 0; i < 8; ++i) {
            float w = wp[lane + i * 64];
#pragma unroll
            for (int bb = 0; bb < 8; ++bb) acc[bb] = fmaf(w, upb[bb][lane + i * 64], acc[bb]);
          }
#pragma unroll
          for (int bb = 0; bb < 8; ++bb) {
            float a = acc[bb];
#pragma unroll
            for (int o = 32; o >= 1; o >>= 1) a += __shfl_xor(a, o, 64);
            if (lane == 0) gst(&tbuf[(size_t)(b0 + bb) * H + n], a);
          }
        }
        gbar_arrive(ctr, bid + 0, blk);
        gbar_wait(ctr, bid + 0, blk);
      } else {
        // gh not needed until step p+1: arrive first, compute while others wait.
        gbar_arrive(ctr, bid + 0, blk);
        for (int rr = 0; rr < 16; ++rr) {
          int m = n0 + rr - H;
          float acc[8];
#pragma unroll
          for (int bb = 0; bb < 8; ++bb) acc[bb] = 0.0f;
          const float* wr = W_hh + (size_t)m * H;
#pragma unroll
          for (int i = 0; i < 16; ++i) {
            float w = wr[lane + i * 64];
#pragma unroll
            for (int bb = 0; bb < 8; ++bb) acc[bb] = fmaf(w, vreg[bb][i], acc[bb]);
          }
          float bias = b_hh[m];
#pragma unroll
          for (int bb = 0; bb < 8; ++bb) {
            float a = acc[bb];
#pragma unroll
            for (int o = 32; o >= 1; o >>= 1) a += __shfl_xor(a, o, 64);
            if (lane == 0) gst(&ghn[(size_t)(b0 + bb) * H3 + m], a + bias);
          }
        }
        gbar_wait(ctr, bid + 0, blk);
      }
    }

    // ---- Phase B: s[b][q] = sum_h tanh(t+WUq)*Vvec; prep rhalf ----
    {
      if (blk < NB) {
        int b = blk;
        float* rb = rhalf + (size_t)b * 1024;
        const float* ub = up + ((size_t)p * NB + b) * 512;
        gst(&rb[tid], ub[tid]);
        gst(&rb[tid + 256], ub[tid + 256]);
        gst(&rb[512 + tid], 0.0f);
        gst(&rb[768 + tid], 0.0f);
      }
      int q = blk;
      const float* wqb = WUq + (size_t)q * NB * H;
      for (int r = 0; r < 8; ++r) {
        int b = wave * 8 + r;
        const float* wq = wqb + (size_t)b * H;
        const float* tb = tbuf + (size_t)b * H;
        const float* vv = Vvec + (size_t)b * H;
        float a = 0.0f;
#pragma unroll
        for (int i = 0; i < 16; ++i) {
          int h = lane + i * 64;
          a += ftanh(gld(tb + h) + wq[h]) * vv[h];
        }
#pragma unroll
        for (int o = 32; o >= 1; o >>= 1) a += __shfl_xor(a, o, 64);
        if (lane == 0) gst(&sbuf[b * LQn + q], a);
      }
    }
    gbar(ctr, bid + 1, blk);

    // ---- Phase C: softmax (redundant per q-slice) + partial c via atomics ----
    {
      int b = blk & 31, qs = blk >> 5;
      float sv = gld(&sbuf[b * LQn + tid]);
      float m = sv;
#pragma unroll
      for (int o = 32; o >= 1; o >>= 1) m = fmaxf(m, __shfl_xor(m, o, 64));
      if (lane == 0) red[wave] = m;
      __syncthreads();
      float bm = fmaxf(fmaxf(red[0], red[1]), fmaxf(red[2], red[3]));
      __syncthreads();
      float e = __expf(sv - bm);
      float se = e;
#pragma unroll
      for (int o = 32; o >= 1; o >>= 1) se += __shfl_xor(se, o, 64);
      if (lane == 0) red[wave] = se;
      __syncthreads();
      float tot = red[0] + red[1] + red[2] + red[3];
      a_s[tid] = e / tot;
      __syncthreads();
      int q0 = qs * 32;
      float acc0 = 0.0f, acc1 = 0.0f;
#pragma unroll 8
      for (int qq = 0; qq < 32; ++qq) {
        float a = a_s[q0 + qq];
        const float* uqr = uq + ((size_t)(q0 + qq) * NB + b) * 512;
        acc0 = fmaf(a, uqr[tid], acc0);
        acc1 = fmaf(a, uqr[tid + 256], acc1);
      }
      atomicAdd(&rhalf[(size_t)b * 1024 + 512 + tid], acc0);
      atomicAdd(&rhalf[(size_t)b * 1024 + 768 + tid], acc1);
    }
    gbar(ctr, bid + 2, blk);

    // ---- Phase D: c_ = sig(rhalf @ Wg2f.T) * c ----
    {
      for (int idx = tid; idx < 8 * 1024; idx += 256) {
        int bb = idx >> 10, k = idx & 1023;
        rh_s[bb][k] = gld(&rhalf[(size_t)(b0 + bb) * 1024 + k]);
      }
      __syncthreads();
      int j0 = s * 16 + wave * 4;
      float rreg[16];
      float accs[4][8];
#pragma unroll
      for (int rr = 0; rr < 4; ++rr)
#pragma unroll
        for (int bb = 0; bb < 8; ++bb) accs[rr][bb] = 0.0f;
      for (int bb = 0; bb < 8; ++bb) {
#pragma unroll
        for (int i = 0; i < 16; ++i) rreg[i] = rh_s[bb][lane + i * 64];
#pragma unroll
        for (int rr = 0; rr < 4; ++rr) {
          const float* wr = Wg2f + (size_t)(j0 + rr) * 1024;
          float a = 0.0f;
#pragma unroll
          for (int i = 0; i < 16; ++i) a = fmaf(wr[lane + i * 64], rreg[i], a);
          accs[rr][bb] = a;
        }
      }
#pragma unroll
      for (int rr = 0; rr < 4; ++rr) {
        int j = j0 + rr;
#pragma unroll
        for (int bb = 0; bb < 8; ++bb) {
          float a = accs[rr][bb];
#pragma unroll
          for (int o = 32; o >= 1; o >>= 1) a += __shfl_xor(a, o, 64);
          if (lane == 0) {
            float cv = rh_s[bb][512 + (j & 511)];
            gst(&cbuf[(size_t)(b0 + bb) * 1024 + j], fsig(a) * cv);
          }
        }
      }
    }
    gbar(ctr, bid + 3, blk);

    // ---- Phase E: gi = c_ @ W_ih.T + b_ih ----
    {
      for (int idx = tid; idx < 8 * 1024; idx += 256) {
        int bb = idx >> 10, k = idx & 1023;
        rh_s[bb][k] = gld(&cbuf[(size_t)(b0 + bb) * 1024 + k]);
      }
      __syncthreads();
      float creg[8][16];
#pragma unroll
      for (int bb = 0; bb < 8; ++bb)
#pragma unroll
        for (int i = 0; i < 16; ++i) creg[bb][i] = rh_s[bb][lane + i * 64];
      int r0 = s * 48 + wave * 12;
      for (int rr = 0; rr < 12; ++rr) {
        int r = r0 + rr;
        const float* wr = W_ih + (size_t)r * 1024;
        float acc[8];
#pragma unroll
        for (int bb = 0; bb < 8; ++bb) acc[bb] = 0.0f;
#pragma unroll
        for (int i = 0; i < 16; ++i) {
          float w = wr[lane + i * 64];
#pragma unroll
          for (int bb = 0; bb < 8; ++bb) acc[bb] = fmaf(w, creg[bb][i], acc[bb]);
        }
        float bias = b_ih[r];
#pragma unroll
        for (int bb = 0; bb < 8; ++bb) {
          float a = acc[bb];
#pragma unroll
          for (int o = 32; o >= 1; o >>= 1) a += __shfl_xor(a, o, 64);
          if (lane == 0) gst(&gibuf[(size_t)(b0 + bb) * H3 + r], a + bias);
        }
      }
    }
    gbar(ctr, bid + 4, blk);
  }

  // ---- final GRU for step 255 ----
  if (tid < 128) {
    int bb = tid >> 4;
    int h = s * 16 + (tid & 15);
    int b = b0 + bb;
    const float* gib = gibuf + (size_t)b * H3;
    const float* ghb = gh1 + (size_t)b * H3;
    float rg = fsig(gld(gib + h) + gld(ghb + h));
    float z = fsig(gld(gib + H + h) + gld(ghb + H + h));
    float nn = ftanh(gld(gib + 2 * H + h) + rg * gld(ghb + 2 * H + h));
    float vn = (1.0f - z) * nn + z * vnew[bb][h];
    out[((size_t)255 * NB + b) * H + h] = vn;
  }
}

extern "C" void kernel_launch(void* const* d_in, const int* in_sizes, int n_in,
                              void* d_out, int out_size, void* d_ws, size_t ws_size,
                              hipStream_t stream) {
  const float* up = (const float*)d_in[0];
  const float* uq = (const float*)d_in[1];
  const float* v0 = (const float*)d_in[2];
  const float* Vvec = (const float*)d_in[3];
  const float* Wp = (const float*)d_in[4];
  const float* Wq = (const float*)d_in[5];
  const float* Wv = (const float*)d_in[6];
  const float* Wg = (const float*)d_in[7];
  const float* W_ih = (const float*)d_in[8];
  const float* W_hh = (const float*)d_in[9];
  const float* b_ih = (const float*)d_in[10];
  const float* b_hh = (const float*)d_in[11];
  float* out = (float*)d_out;
  float* ws = (float*)d_ws;

  float* tbuf = ws;                    // 32768
  float* gh0 = ws + 32768;             // 98304
  float* gh1 = ws + 131072;            // 98304
  float* sbuf = ws + 229376;           // 8192
  float* rhalf = ws + 237568;          // 32768
  float* cbuf = ws + 270336;           // 32768
  float* gibuf = ws + 303104;          // 98304
  float* Wpf = ws + 401408;            // 524288
  float* Wg2f = ws + 925696;           // 1048576
  float* WUq = ws + 1974272;           // 8388608
  unsigned* ctr = (unsigned*)(ws + 10362880);  // 1280*272 uints = 1.36 MB

  k_init<<<4096, 256, 0, stream>>>(Wp, Wg, Wpf, Wg2f);
  k_zero<<<1360, 256, 0, stream>>>(ctr);
  k_wuq<<<dim3(128, 16), 256, 0, stream>>>(uq, Wq, WUq);
  k_scan<<<256, 256, 0, stream>>>(up, uq, v0, Vvec, Wv, W_hh, b_hh, W_ih, b_ih,
                                  Wpf, Wg2f, WUq, tbuf, gh0, gh1, sbuf, rhalf,
                                  cbuf, gibuf, out, ctr);
}

// Round 5
// 33656.497 us; speedup vs baseline: 2.1793x; 1.6854x over previous
//
#include <hip/hip_runtime.h>

// PQMatcher persistent-kernel v4.
// R4 post-mortem: time was miss-latency serialization (scalar loads, 4 waves/CU,
// MLP ~6) + sc1 staging volume, not barrier atomics. v4: 512 thr/block,
// float4 loads for all read-only data, GRU owner-computed in phase E (gibuf
// eliminated), B re-sliced (bgroup x q-slice) with LDS t-staging, C re-sliced
// (b x i-chunk) without atomics. 5 relaxed tree barriers/step, fence-free:
// all cross-block mutable data via relaxed agent-scope (sc1/L3) ld/st.

#define NB 32
#define H 1024
#define LQn 256

__device__ __forceinline__ float fsig(float x) { return 1.0f / (1.0f + __expf(-x)); }
__device__ __forceinline__ float ftanh(float x) { return 1.0f - 2.0f / (1.0f + __expf(2.0f * x)); }

__device__ __forceinline__ float gld(const float* p) {
  return __hip_atomic_load(p, __ATOMIC_RELAXED, __HIP_MEMORY_SCOPE_AGENT);
}
__device__ __forceinline__ void gst(float* p, float v) {
  __hip_atomic_store(p, v, __ATOMIC_RELAXED, __HIP_MEMORY_SCOPE_AGENT);
}
__device__ __forceinline__ float dot4(float4 a, float4 b, float acc) {
  acc = fmaf(a.x, b.x, acc); acc = fmaf(a.y, b.y, acc);
  acc = fmaf(a.z, b.z, acc); acc = fmaf(a.w, b.w, acc); return acc;
}
__device__ __forceinline__ float wred(float a) {
#pragma unroll
  for (int o = 32; o >= 1; o >>= 1) a += __shfl_xor(a, o, 64);
  return a;
}

#define BAR_STRIDE 272
#define N_BAR 1280

__device__ __forceinline__ void gbar_arrive(unsigned* __restrict__ ctr, int id, int blk) {
  __syncthreads();  // vmcnt(0) drain: sc1 data stores complete at L3
  if (threadIdx.x == 0) {
    unsigned* base = ctr + (size_t)id * BAR_STRIDE;
    unsigned o = __hip_atomic_fetch_add(base + (blk & 7) * 16, 1u,
                                        __ATOMIC_RELAXED, __HIP_MEMORY_SCOPE_AGENT);
    if (o == 31u) {
      unsigned r = __hip_atomic_fetch_add(base + 128, 1u,
                                          __ATOMIC_RELAXED, __HIP_MEMORY_SCOPE_AGENT);
      if (r == 7u) {
#pragma unroll
        for (int l = 0; l < 8; ++l)
          __hip_atomic_store(base + 144 + l * 16, 1u,
                             __ATOMIC_RELAXED, __HIP_MEMORY_SCOPE_AGENT);
      }
    }
  }
}
__device__ __forceinline__ void gbar_wait(unsigned* __restrict__ ctr, int id, int blk) {
  if (threadIdx.x == 0) {
    unsigned* my = ctr + (size_t)id * BAR_STRIDE + 144 + (blk >> 5) * 16;
    while (__hip_atomic_load(my, __ATOMIC_RELAXED, __HIP_MEMORY_SCOPE_AGENT) == 0u)
      __builtin_amdgcn_s_sleep(1);
  }
  __syncthreads();
}
__device__ __forceinline__ void gbar(unsigned* __restrict__ ctr, int id, int blk) {
  gbar_arrive(ctr, id, blk);
  gbar_wait(ctr, id, blk);
}

// ---------------- init: weight folds + v0 copy ----------------
__global__ __launch_bounds__(256) void k_init(
    const float* __restrict__ v0, const float* __restrict__ Wp,
    const float* __restrict__ Wg, float* __restrict__ vbuf,
    float* __restrict__ Wpf, float* __restrict__ Wguf, float* __restrict__ Wgcf) {
  int i = blockIdx.x * 256 + threadIdx.x;
  if (i < NB * H) vbuf[i] = v0[i];
  if (i < 1024 * 512) {
    int n = i >> 9, k = i & 511;
    Wpf[i] = Wp[(size_t)n * 1024 + k] + Wp[(size_t)n * 1024 + k + 512];
    const float* wr = Wg + (size_t)(1024 + n) * 2048;
    Wguf[i] = wr[k] + wr[k + 512];
    Wgcf[i] = wr[1024 + k] + wr[1536 + k];
  }
}

__global__ __launch_bounds__(256) void k_zero(unsigned* __restrict__ ctr) {
  int i = blockIdx.x * 256 + threadIdx.x;
  if (i < N_BAR * BAR_STRIDE) ctr[i] = 0u;
}

// ---------------- WUq = uq @ Wqf.T : [8192,512] x [512,1024] ----------------
__global__ __launch_bounds__(256) void k_wuq(
    const float* __restrict__ A, const float* __restrict__ Wq, float* __restrict__ C) {
  __shared__ float As[16][65];
  __shared__ float Bs[16][65];
  int bm = blockIdx.x * 64, bn = blockIdx.y * 64;
  int t = threadIdx.x;
  int tx = t & 15, ty = t >> 4;
  float acc[4][4] = {};
  for (int k0 = 0; k0 < 512; k0 += 16) {
#pragma unroll
    for (int l = 0; l < 4; ++l) {
      int idx = t + l * 256;
      int row = idx >> 4, kk = idx & 15;
      As[kk][row] = A[(size_t)(bm + row) * 512 + k0 + kk];
      Bs[kk][row] = Wq[(size_t)(bn + row) * 1024 + k0 + kk] +
                    Wq[(size_t)(bn + row) * 1024 + k0 + kk + 512];
    }
    __syncthreads();
#pragma unroll
    for (int kk = 0; kk < 16; ++kk) {
      float a0[4], b0[4];
#pragma unroll
      for (int i = 0; i < 4; ++i) a0[i] = As[kk][ty * 4 + i];
#pragma unroll
      for (int j = 0; j < 4; ++j) b0[j] = Bs[kk][tx * 4 + j];
#pragma unroll
      for (int i = 0; i < 4; ++i)
#pragma unroll
        for (int j = 0; j < 4; ++j) acc[i][j] += a0[i] * b0[j];
    }
    __syncthreads();
  }
#pragma unroll
  for (int i = 0; i < 4; ++i)
#pragma unroll
    for (int j = 0; j < 4; ++j)
      C[(size_t)(bm + ty * 4 + i) * 1024 + bn + tx * 4 + j] = acc[i][j];
}

// ---------------- persistent scan kernel ----------------
__global__ __launch_bounds__(512, 1) void k_scan(
    const float* __restrict__ up, const float* __restrict__ uq,
    const float* __restrict__ Vvec, const float* __restrict__ Wv,
    const float* __restrict__ W_hh, const float* __restrict__ b_hh,
    const float* __restrict__ W_ih, const float* __restrict__ b_ih,
    const float* __restrict__ Wpf, const float* __restrict__ Wguf,
    const float* __restrict__ Wgcf, const float* __restrict__ WUq,
    float* __restrict__ vbuf, float* __restrict__ tbuf, float* __restrict__ ghbuf,
    float* __restrict__ sbuf, float* __restrict__ cbuf, float* __restrict__ c_buf,
    float* __restrict__ out, unsigned* __restrict__ ctr) {
  const int blk = blockIdx.x, tid = threadIdx.x;
  const int lane = tid & 63, wave = tid >> 6;  // 8 waves
  const int s = blk & 63, bg = blk >> 6, b0 = bg * 8;
  __shared__ float shm[8704];  // [0..8192): staging; [8192..8576): gi_s

  for (int p = 0; p < 256; ++p) {
    const int bid = p * 5;

    // ================= Phase A: t = Wv.v + Wpf.up ; gh = W_hh.v + b_hh ====
    for (int i = tid; i < 8192; i += 512) shm[i] = gld(vbuf + (size_t)b0 * H + i);
    __syncthreads();
    {
      float4 vr[8][4];
#pragma unroll
      for (int bb = 0; bb < 8; ++bb) {
        const float4* v4 = (const float4*)(shm + bb * 1024);
#pragma unroll
        for (int i = 0; i < 4; ++i) vr[bb][i] = v4[lane + i * 64];
      }
      const bool is_t = (s < 16);
      if (is_t) {
        for (int rr = 0; rr < 8; ++rr) {
          int n = s * 64 + wave * 8 + rr;
          const float4* wv4 = (const float4*)(Wv + (size_t)n * H);
          float4 w0 = wv4[lane], w1 = wv4[lane + 64], w2 = wv4[lane + 128], w3 = wv4[lane + 192];
          const float4* wp4 = (const float4*)(Wpf + (size_t)n * 512);
          float4 q0 = wp4[lane], q1 = wp4[lane + 64];
#pragma unroll
          for (int bb = 0; bb < 8; ++bb) {
            const float4* u4 = (const float4*)(up + ((size_t)p * NB + b0 + bb) * 512);
            float a = 0.0f;
            a = dot4(w0, vr[bb][0], a); a = dot4(w1, vr[bb][1], a);
            a = dot4(w2, vr[bb][2], a); a = dot4(w3, vr[bb][3], a);
            a = dot4(q0, u4[lane], a); a = dot4(q1, u4[lane + 64], a);
            a = wred(a);
            if (lane == 0) gst(&tbuf[(size_t)(b0 + bb) * H + n], a);
          }
        }
        gbar_arrive(ctr, bid + 0, blk);
        gbar_wait(ctr, bid + 0, blk);
      } else {
        // gh consumed only in phase E: arrive first, compute into the gap.
        gbar_arrive(ctr, bid + 0, blk);
        for (int rr = 0; rr < 8; ++rr) {
          int m = s * 64 + wave * 8 + rr - 1024;
          const float4* wh4 = (const float4*)(W_hh + (size_t)m * H);
          float4 w0 = wh4[lane], w1 = wh4[lane + 64], w2 = wh4[lane + 128], w3 = wh4[lane + 192];
          float bias = b_hh[m];
#pragma unroll
          for (int bb = 0; bb < 8; ++bb) {
            float a = 0.0f;
            a = dot4(w0, vr[bb][0], a); a = dot4(w1, vr[bb][1], a);
            a = dot4(w2, vr[bb][2], a); a = dot4(w3, vr[bb][3], a);
            a = wred(a);
            if (lane == 0) gst(&ghbuf[(size_t)(b0 + bb) * 3072 + m], a + bias);
          }
        }
        gbar_wait(ctr, bid + 0, blk);
      }
    }

    // ================= Phase B: s[b][q] = sum_h tanh(t + WUq) * Vvec ======
    {
      for (int i = tid; i < 8192; i += 512) shm[i] = gld(tbuf + (size_t)b0 * H + i);
      __syncthreads();
#pragma unroll
      for (int j = 0; j < 4; ++j) {
        int pp = wave * 4 + j;           // 32 pairs: 4 q x 8 b
        int qq = s * 4 + (pp & 3);
        int bb = pp >> 2;
        const float4* wq4 = (const float4*)(WUq + ((size_t)qq * NB + b0 + bb) * H);
        const float4* vv4 = (const float4*)(Vvec + (size_t)(b0 + bb) * H);
        const float4* tt4 = (const float4*)(shm + bb * 1024);
        float a = 0.0f;
#pragma unroll
        for (int i = 0; i < 4; ++i) {
          float4 w = wq4[lane + i * 64];
          float4 t = tt4[lane + i * 64];
          float4 v = vv4[lane + i * 64];
          a = fmaf(ftanh(t.x + w.x), v.x, a);
          a = fmaf(ftanh(t.y + w.y), v.y, a);
          a = fmaf(ftanh(t.z + w.z), v.z, a);
          a = fmaf(ftanh(t.w + w.w), v.w, a);
        }
        a = wred(a);
        if (lane == 0) gst(&sbuf[(b0 + bb) * LQn + qq], a);
      }
    }
    gbar(ctr, bid + 1, blk);

    // ================= Phase C: softmax + c-chunk =========================
    {
      int b = blk & 31, ch = blk >> 5, i0 = ch * 64;
      float* a_s = shm;           // 256
      float* part = shm + 256;    // 512
      float* red = shm + 768;     // 16
      float sv = (tid < 256) ? gld(&sbuf[b * LQn + tid]) : -1e30f;
      float m = sv;
#pragma unroll
      for (int o = 32; o >= 1; o >>= 1) m = fmaxf(m, __shfl_xor(m, o, 64));
      if (lane == 0) red[wave] = m;
      __syncthreads();
      float bm = red[0];
#pragma unroll
      for (int w = 1; w < 8; ++w) bm = fmaxf(bm, red[w]);
      __syncthreads();
      float e = (tid < 256) ? __expf(sv - bm) : 0.0f;
      float se = wred(e);
      if (lane == 0) red[wave] = se;
      __syncthreads();
      float tot = red[0] + red[1] + red[2] + red[3] + red[4] + red[5] + red[6] + red[7];
      if (tid < 256) a_s[tid] = e / tot;
      __syncthreads();
      float acc = 0.0f;
#pragma unroll 8
      for (int k = 0; k < 32; ++k) {
        int q = wave * 32 + k;
        acc = fmaf(a_s[q], uq[((size_t)q * NB + b) * 512 + i0 + lane], acc);
      }
      part[wave * 64 + lane] = acc;
      __syncthreads();
      if (tid < 64) {
        float c = 0.0f;
#pragma unroll
        for (int w = 0; w < 8; ++w) c += part[w * 64 + tid];
        gst(&cbuf[(size_t)b * 512 + i0 + tid], c);
      }
    }
    gbar(ctr, bid + 2, blk);

    // ================= Phase D: c_ = sig(Wguf.up + Wgcf.c) * c ============
    {
      for (int i = tid; i < 4096; i += 512) shm[i] = gld(cbuf + (size_t)b0 * 512 + i);
      __syncthreads();
      int bb = wave;
      const float4* uu4 = (const float4*)(up + ((size_t)p * NB + b0 + bb) * 512);
      float4 u0 = uu4[lane], u1 = uu4[lane + 64];
      const float4* cc4 = (const float4*)(shm + bb * 512);
      float4 c0 = cc4[lane], c1 = cc4[lane + 64];
      for (int k = 0; k < 16; ++k) {
        int j = s * 16 + k;
        const float4* wu4 = (const float4*)(Wguf + (size_t)j * 512);
        const float4* wc4 = (const float4*)(Wgcf + (size_t)j * 512);
        float a = 0.0f;
        a = dot4(wu4[lane], u0, a); a = dot4(wu4[lane + 64], u1, a);
        a = dot4(wc4[lane], c0, a); a = dot4(wc4[lane + 64], c1, a);
        a = wred(a);
        if (lane == 0) {
          float cv = shm[bb * 512 + (j & 511)];
          gst(&c_buf[(size_t)(b0 + bb) * H + j], fsig(a) * cv);
        }
      }
    }
    gbar(ctr, bid + 3, blk);

    // ================= Phase E: gi = W_ih.c_ + b_ih ; GRU -> v ============
    {
      for (int i = tid; i < 8192; i += 512) shm[i] = gld(c_buf + (size_t)b0 * H + i);
      __syncthreads();
      float* gi_s = shm + 8192;  // [48][8]
      int h0 = s * 16;
#pragma unroll
      for (int e = 0; e < 6; ++e) {
        int rw = wave * 6 + e;              // 0..47
        int gate = rw >> 4, hh = rw & 15;
        int r = gate * 1024 + h0 + hh;
        const float4* wi4 = (const float4*)(W_ih + (size_t)r * H);
        float4 w0 = wi4[lane], w1 = wi4[lane + 64], w2 = wi4[lane + 128], w3 = wi4[lane + 192];
        float bias = b_ih[r];
#pragma unroll
        for (int bb = 0; bb < 8; ++bb) {
          const float4* cc4 = (const float4*)(shm + bb * 1024);
          float a = 0.0f;
          a = dot4(w0, cc4[lane], a); a = dot4(w1, cc4[lane + 64], a);
          a = dot4(w2, cc4[lane + 128], a); a = dot4(w3, cc4[lane + 192], a);
          a = wred(a);
          if (lane == 0) gi_s[rw * 8 + bb] = a + bias;
        }
      }
      __syncthreads();
      if (tid < 128) {
        int hh = tid & 15, bb = tid >> 4;
        int h = h0 + hh, b = b0 + bb;
        float gir = gi_s[hh * 8 + bb];
        float giz = gi_s[(16 + hh) * 8 + bb];
        float gin = gi_s[(32 + hh) * 8 + bb];
        const float* ghb = ghbuf + (size_t)b * 3072;
        float ghr = gld(ghb + h);
        float ghz = gld(ghb + 1024 + h);
        float ghn = gld(ghb + 2048 + h);
        float vold = gld(&vbuf[(size_t)b * H + h]);
        float rg = fsig(gir + ghr);
        float z = fsig(giz + ghz);
        float nn = ftanh(gin + rg * ghn);
        float vn = (1.0f - z) * nn + z * vold;
        gst(&vbuf[(size_t)b * H + h], vn);
        out[((size_t)p * NB + b) * H + h] = vn;
      }
    }
    gbar(ctr, bid + 4, blk);
  }
}

extern "C" void kernel_launch(void* const* d_in, const int* in_sizes, int n_in,
                              void* d_out, int out_size, void* d_ws, size_t ws_size,
                              hipStream_t stream) {
  const float* up = (const float*)d_in[0];
  const float* uq = (const float*)d_in[1];
  const float* v0 = (const float*)d_in[2];
  const float* Vvec = (const float*)d_in[3];
  const float* Wp = (const float*)d_in[4];
  const float* Wq = (const float*)d_in[5];
  const float* Wv = (const float*)d_in[6];
  const float* Wg = (const float*)d_in[7];
  const float* W_ih = (const float*)d_in[8];
  const float* W_hh = (const float*)d_in[9];
  const float* b_ih = (const float*)d_in[10];
  const float* b_hh = (const float*)d_in[11];
  float* out = (float*)d_out;
  float* ws = (float*)d_ws;

  float* vbuf  = ws;                   // 32768
  float* tbuf  = ws + 32768;           // 32768
  float* ghbuf = ws + 65536;           // 98304
  float* sbuf  = ws + 163840;          // 8192
  float* cbuf  = ws + 172032;          // 16384
  float* c_buf = ws + 188416;          // 32768
  float* Wpf   = ws + 221184;          // 524288
  float* Wguf  = ws + 745472;          // 524288
  float* Wgcf  = ws + 1269760;         // 524288
  float* WUq   = ws + 1794048;         // 8388608
  unsigned* ctr = (unsigned*)(ws + 10182656);  // 348160 uints

  k_init<<<2048, 256, 0, stream>>>(v0, Wp, Wg, vbuf, Wpf, Wguf, Wgcf);
  k_zero<<<1360, 256, 0, stream>>>(ctr);
  k_wuq<<<dim3(128, 16), 256, 0, stream>>>(uq, Wq, WUq);
  k_scan<<<256, 512, 0, stream>>>(up, uq, Vvec, Wv, W_hh, b_hh, W_ih, b_ih,
                                  Wpf, Wguf, Wgcf, WUq, vbuf, tbuf, ghbuf,
                                  sbuf, cbuf, c_buf, out, ctr);
}